// Round 11
// baseline (232.946 us; speedup 1.0000x reference)
//
#include <hip/hip_runtime.h>
#include <stdint.h>

#define Bb 8
#define NN 131072           // candidates per batch (H*W*A)
#define PREK 1024
#define POSTK 300
#define NBIN 120            // scores 9..127 -> bin = s-9

__device__ __forceinline__ float clampb(float v){ return fminf(fmaxf(v, 0.0f), 1024.0f); }

// K1: per-(b,h) block: best score + first-argmax for its 1024 candidates (int4 loads),
//     LDS transpose to candidate-index order, coalesced sc16 write, global hist atomics.
__global__ void __launch_bounds__(256) k1_scores(const int* __restrict__ data,
                                                 unsigned short* __restrict__ sc16,
                                                 int* __restrict__ ghist){
    int blk = blockIdx.x;                 // 8*128: (b, h)
    int b = blk >> 7, h = blk & 127;
    int tid = threadIdx.x;
    int a = tid >> 5, wg = tid & 31;
    int w = wg << 2;
    const int* p = data + (((size_t)(b*96 + a*12 + 4)) << 14) + (h << 7) + w;
    int4 m = *(const int4*)p;
    int4 lb = make_int4(0,0,0,0);
#pragma unroll
    for (int c = 1; c < 8; ++c){
        int4 v = *(const int4*)(p + ((size_t)c << 14));
        if (v.x > m.x){ m.x = v.x; lb.x = c; }
        if (v.y > m.y){ m.y = v.y; lb.y = c; }
        if (v.z > m.z){ m.z = v.z; lb.z = c; }
        if (v.w > m.w){ m.w = v.w; lb.w = c; }
    }
    __shared__ unsigned short st[1024];
    __shared__ int hist[NBIN];
    for (int i = tid; i < NBIN; i += 256) hist[i] = 0;
    st[(w+0)*8 + a] = (unsigned short)(((m.x + 128) << 8) | lb.x);
    st[(w+1)*8 + a] = (unsigned short)(((m.y + 128) << 8) | lb.y);
    st[(w+2)*8 + a] = (unsigned short)(((m.z + 128) << 8) | lb.z);
    st[(w+3)*8 + a] = (unsigned short)(((m.w + 128) << 8) | lb.w);
    __syncthreads();
    if (m.x >= 9) atomicAdd(&hist[m.x-9], 1);
    if (m.y >= 9) atomicAdd(&hist[m.y-9], 1);
    if (m.z >= 9) atomicAdd(&hist[m.z-9], 1);
    if (m.w >= 9) atomicAdd(&hist[m.w-9], 1);
    // coalesced candidate-order write: n = h*1024 + (w*8 + a)
    ushort4* dst = (ushort4*)(sc16 + (((size_t)b) << 17) + (h << 10));
    dst[tid] = ((const ushort4*)st)[tid];
    __syncthreads();
    if (tid < NBIN && hist[tid]) atomicAdd(&ghist[(b << 7) + tid], hist[tid]);
}

// NG-templated register NMS (verbatim from verified round-10 kernel)
template<int NG>
__device__ __forceinline__ void nms_reg(const float* __restrict__ X1, const float* __restrict__ Y1,
                                        const float* __restrict__ X2, const float* __restrict__ Y2,
                                        const float* __restrict__ AR,
                                        int base, int M, int lane, unsigned char* __restrict__ KEEP){
    float rx1[NG], ry1[NG], rx2[NG], ry2[NG], rar[NG];
#pragma unroll
    for (int g = 0; g < NG; ++g){
        int r = g*64 + lane;
        int ad = base + ((r < M) ? r : 0);
        rx1[g]=X1[ad]; ry1[g]=Y1[ad]; rx2[g]=X2[ad]; ry2[g]=Y2[ad]; rar[g]=AR[ad];
    }
    unsigned long long mk[NG][NG];
#pragma unroll
    for (int g = 0; g < NG; ++g)
#pragma unroll
        for (int c = 0; c < NG; ++c) mk[g][c] = 0ull;
#pragma unroll
    for (int jw = 0; jw < NG; ++jw){
        if (jw*64 < M){
            int limj = M - jw*64; if (limj > 64) limj = 64;
#pragma unroll 4
            for (int jl = 0; jl < 64; ++jl){
                if (jl < limj){
                    float jx1 = __shfl(rx1[jw], jl);
                    float jy1 = __shfl(ry1[jw], jl);
                    float jx2 = __shfl(rx2[jw], jl);
                    float jy2 = __shfl(ry2[jw], jl);
                    float jar = __fmul_rn(__fsub_rn(jx2, jx1), __fsub_rn(jy2, jy1));
#pragma unroll
                    for (int g = 0; g < NG; ++g){
                        if (g > jw) continue;
                        bool jgi = (g < jw) ? true : (lane < jl);
                        float wx = fmaxf(__fsub_rn(fminf(rx2[g], jx2), fmaxf(rx1[g], jx1)), 0.0f);
                        float wy = fmaxf(__fsub_rn(fminf(ry2[g], jy2), fmaxf(ry1[g], jy1)), 0.0f);
                        float inter = __fmul_rn(wx, wy);
                        float den = __fadd_rn(__fsub_rn(__fadd_rn(rar[g], jar), inter), 1e-9f);
                        bool o = (__fdiv_rn(inter, den) > 0.5f) && jgi;
                        mk[g][jw] |= o ? (1ull << jl) : 0ull;
                    }
                }
            }
        }
    }
    unsigned long long rem[NG];
#pragma unroll
    for (int g = 0; g < NG; ++g) rem[g] = 0ull;
#pragma unroll
    for (int iw = 0; iw < NG; ++iw){
        if (iw*64 < M){
            int limi = M - iw*64; if (limi > 64) limi = 64;
#pragma unroll 4
            for (int il = 0; il < 64; ++il){
                if (il < limi){
                    unsigned long long msk = ((rem[iw] >> il) & 1ull) ? 0ull : ~0ull;
#pragma unroll
                    for (int w = iw; w < NG; ++w){
                        unsigned long long rw = __shfl(mk[iw][w], il);
                        rem[w] |= rw & msk;
                    }
                }
            }
        }
    }
#pragma unroll
    for (int g = 0; g < NG; ++g){
        int r = g*64 + lane;
        if (r < M) KEEP[base + r] = (unsigned char)(((rem[g] >> lane) & 1ull) ^ 1ull);
    }
}

// KB: per batch (1024 thr): suffix/T -> stable counting-rank (2-pass + LDS scan) ->
//     decode -> partition -> NMS -> compaction. No intermediate global buffers.
__global__ void __launch_bounds__(1024) kB(const unsigned short* __restrict__ sc16,
                                           const int* __restrict__ ghist,
                                           const int* __restrict__ data,
                                           const float* __restrict__ anchors,
                                           const int* __restrict__ etab,
                                           float* __restrict__ out){
    int b = blockIdx.x, tid = threadIdx.x, lane = tid & 63, wv = tid >> 6;
    __shared__ int cntX[2048*4];           // 32 KB: phase C counts; reused as box arrays after
    __shared__ int ridx[PREK];
    __shared__ unsigned short rsc[PREK];
    __shared__ int hist[128], gt[128], suf[128];
    __shared__ int Tsh;
    __shared__ int wq[16][8];
    __shared__ int ccn[8], cbs[8];
    __shared__ int wcn[16];
    __shared__ int totS;

    float* X1 = (float*)cntX;              // aliases (cntX dead after phase C)
    float* Y1 = X1 + 1024; float* X2 = Y1 + 1024; float* Y2 = X2 + 1024;
    float* AR = Y2 + 1024;
    unsigned char* KEEP = (unsigned char*)(AR + 1024);

    const unsigned short* sb = sc16 + (((size_t)b) << 17);

    // ---- phase B: hist -> suffix -> gt / T ----
    if (tid == 0) Tsh = -1;
    if (tid < 128) hist[tid] = (tid < NBIN) ? ghist[(b << 7) + tid] : 0;
    ridx[tid] = -1;
    __syncthreads();
    if (tid < 128) suf[tid] = hist[tid];
    __syncthreads();
    for (int off = 1; off < 128; off <<= 1){
        int v = 0;
        if (tid < 128 && tid + off < 128) v = suf[tid + off];
        __syncthreads();
        if (tid < 128) suf[tid] += v;
        __syncthreads();
    }
    if (tid < NBIN){
        gt[tid] = suf[tid] - hist[tid];
        if (suf[tid] >= PREK) atomicMax(&Tsh, tid);
    }
    __syncthreads();
    int T = Tsh > 0 ? Tsh : 0;

    // ---- phase C: stable counting-rank, 4 bins per group ----
    for (int g0 = T; g0 < NBIN; g0 += 4){
        // pass 1: per-(k,wave,slot) counts
        for (int k = 0; k < 128; ++k){
            int bin = (int)(sb[(k << 10) + tid] >> 8) - 137;   // = score - 9
#pragma unroll
            for (int s = 0; s < 4; ++s){
                unsigned long long bal = __ballot(bin == g0 + s);
                if (lane == 0) cntX[(((k << 4) + wv) << 2) + s] = __popcll(bal);
            }
        }
        __syncthreads();
        // exclusive scan over e = k*16+wv (2048) per slot (Hillis-Steele, 8 elems/thread)
        int orig[8];
#pragma unroll
        for (int j = 0; j < 8; ++j) orig[j] = cntX[tid*8 + j];
        for (int off = 1; off < 2048; off <<= 1){
            int rd[8];
#pragma unroll
            for (int j = 0; j < 8; ++j){
                int e = 2*tid + (j >> 2), s = j & 3;
                rd[j] = (e >= off) ? cntX[((e - off) << 2) + s] : 0;
            }
            __syncthreads();
#pragma unroll
            for (int j = 0; j < 8; ++j) cntX[tid*8 + j] += rd[j];
            __syncthreads();
        }
#pragma unroll
        for (int j = 0; j < 8; ++j) cntX[tid*8 + j] -= orig[j];
        __syncthreads();
        // pass 2: stable scatter by absolute rank
        for (int k = 0; k < 128; ++k){
            int n = (k << 10) + tid;
            unsigned short v = sb[n];
            int bin = (int)(v >> 8) - 137;
#pragma unroll
            for (int s = 0; s < 4; ++s){
                unsigned long long bal = __ballot(bin == g0 + s);
                if (bin == g0 + s){
                    int myeq = __popcll(bal & ((1ull << lane) - 1ull));
                    int rank = gt[bin] + cntX[(((k << 4) + wv) << 2) + s] + myeq;
                    if (rank < PREK){ rsc[rank] = v; ridx[rank] = n; }
                }
            }
        }
        __syncthreads();
    }

    // ---- phase D: decode ranked candidates (bit-exact, verbatim k3 math) ----
    int n = ridx[tid];
    bool valid = (n >= 0);
    unsigned short v = valid ? rsc[tid] : (unsigned short)0;
    int lc = valid ? (v & 255) : -1;
    float sval = valid ? __fmul_rn((float)((int)(v >> 8) - 128), 0.0625f) : 0.0f;
    float bx1=0.f, by1=0.f, bx2=0.f, by2=0.f;
    if (valid){
        int a = n & 7, hh = n >> 10, wc = (n >> 3) & 127;
        const int* p = data + (((size_t)(b*96 + a*12)) << 14) + (hh << 7) + wc;
        int d0 = p[0], d1 = p[1 << 14], d2 = p[2 << 14], d3 = p[3 << 14];
        float4 an = ((const float4*)anchors)[n];
        float cx = __fmul_rn(__fadd_rn(an.x, an.z), 0.5f);
        float cy = __fmul_rn(__fadd_rn(an.y, an.w), 0.5f);
        float wx = __fsub_rn(an.z, an.x), wy = __fsub_rn(an.w, an.y);
        float dx = __fmul_rn((float)d0, 0.0625f), dy = __fmul_rn((float)d1, 0.0625f);
        float ex = __fmul_rn((float)etab[d2 + 128], 0.0625f);
        float ey = __fmul_rn((float)etab[d3 + 128], 0.0625f);
        float pcx = __fadd_rn(cx, __fmul_rn(dx, wx));
        float pcy = __fadd_rn(cy, __fmul_rn(dy, wy));
        float hx = __fmul_rn(__fmul_rn(wx, ex), 0.5f);
        float hy = __fmul_rn(__fmul_rn(wy, ey), 0.5f);
        bx1 = clampb(__fsub_rn(pcx, hx)); by1 = clampb(__fsub_rn(pcy, hy));
        bx2 = clampb(__fadd_rn(pcx, hx)); by2 = clampb(__fadd_rn(pcy, hy));
    }

    // ---- phase E: stable per-class partition (verbatim round-5) ----
    KEEP[tid] = 0;
    int win = 0;
#pragma unroll
    for (int c = 0; c < 8; ++c){
        unsigned long long bal = __ballot(lc == c);
        if (lane == 0) wq[wv][c] = __popcll(bal);
        if (lc == c) win = __popcll(bal & ((1ull << lane) - 1ull));
    }
    __syncthreads();
    if (tid < 8){
        int run = 0;
        for (int w2 = 0; w2 < 16; ++w2){ int t = wq[w2][tid]; wq[w2][tid] = run; run += t; }
        ccn[tid] = run;
    }
    __syncthreads();
    if (tid == 0){
        int run = 0;
        for (int c = 0; c < 8; ++c){ cbs[c] = run; run += ccn[c]; }
    }
    __syncthreads();
    int pp = 0;
    if (valid){
        pp = cbs[lc] + wq[wv][lc] + win;
        float off = (float)(lc << 12);
        float ox1 = __fadd_rn(bx1, off), oy1 = __fadd_rn(by1, off);
        float ox2 = __fadd_rn(bx2, off), oy2 = __fadd_rn(by2, off);
        X1[pp] = ox1; Y1[pp] = oy1; X2[pp] = ox2; Y2[pp] = oy2;
        AR[pp] = __fmul_rn(__fsub_rn(ox2, ox1), __fsub_rn(oy2, oy1));
    }
    __syncthreads();

    // ---- phase F: NMS, one wave per class (waves 8..15 idle) ----
    if (wv < 8){
        int M = ccn[wv], base = cbs[wv];
        if (M > 0){
            if (M <= 128)      nms_reg<2>(X1, Y1, X2, Y2, AR, base, M, lane, KEEP);
            else if (M <= 192) nms_reg<3>(X1, Y1, X2, Y2, AR, base, M, lane, KEEP);
            else if (M <= 256) nms_reg<4>(X1, Y1, X2, Y2, AR, base, M, lane, KEEP);
            else {
                for (int m = lane; m < M; m += 64) KEEP[base+m] = 0;   // 1 = suppressed
                for (int i = 0; i < M; ++i){
                    if (KEEP[base+i]) continue;
                    float xi1 = X1[base+i], yi1 = Y1[base+i];
                    float xi2 = X2[base+i], yi2 = Y2[base+i], ai = AR[base+i];
                    for (int j = i + 1 + lane; j < M; j += 64){
                        if (KEEP[base+j]) continue;
                        float wx = fmaxf(__fsub_rn(fminf(xi2, X2[base+j]), fmaxf(xi1, X1[base+j])), 0.0f);
                        float wy = fmaxf(__fsub_rn(fminf(yi2, Y2[base+j]), fmaxf(yi1, Y1[base+j])), 0.0f);
                        float inter = __fmul_rn(wx, wy);
                        float den = __fadd_rn(__fsub_rn(__fadd_rn(ai, AR[base+j]), inter), 1e-9f);
                        if (__fdiv_rn(inter, den) > 0.5f) KEEP[base+j] = 1;
                    }
                }
                for (int m = lane; m < M; m += 64) KEEP[base+m] ^= 1;  // -> 1 = keep
            }
        }
    }
    __syncthreads();

    // ---- phase G: rank-ordered compaction to first 300 (verbatim round-5) ----
    bool kp = valid && (KEEP[pp] != 0);
    unsigned long long bal = __ballot(kp);
    if (lane == 0) wcn[wv] = __popcll(bal);
    __syncthreads();
    if (tid == 0){
        int r = 0;
        for (int w2 = 0; w2 < 16; ++w2){ int t = wcn[w2]; wcn[w2] = r; r += t; }
        totS = r;
    }
    __syncthreads();
    int pos = wcn[wv] + __popcll(bal & ((1ull << lane) - 1ull));
    float* boxes  = out;
    float* scores = out + Bb*POSTK*4;
    float* labs   = out + Bb*POSTK*5;
    if (kp && pos < POSTK){
        int o = (b*POSTK + pos)*4;
        boxes[o+0] = bx1; boxes[o+1] = by1; boxes[o+2] = bx2; boxes[o+3] = by2;
        scores[b*POSTK + pos] = sval;
        labs[b*POSTK + pos] = (float)lc;
    }
    int tot = totS < POSTK ? totS : POSTK;
    if (tid >= tot && tid < POSTK){
        int o = (b*POSTK + tid)*4;
        boxes[o+0] = 0.f; boxes[o+1] = 0.f; boxes[o+2] = 0.f; boxes[o+3] = 0.f;
        scores[b*POSTK + tid] = 0.f;
        labs[b*POSTK + tid] = -1.0f;
    }
}

extern "C" void kernel_launch(void* const* d_in, const int* in_sizes, int n_in,
                              void* d_out, int out_size, void* d_ws, size_t ws_size,
                              hipStream_t stream) {
    const int*   data    = (const int*)d_in[0];
    const float* anchors = (const float*)d_in[1];
    const int*   etab    = (const int*)d_in[2];
    float* out = (float*)d_out;

    char* ws = (char*)d_ws;
    size_t off = 0;
    auto alloc = [&](size_t bytes)->char*{ char* p = ws + off; off += (bytes + 255) & ~(size_t)255; return p; };
    unsigned short* sc16 = (unsigned short*)alloc((size_t)Bb*NN*2);   // 2 MB
    int* ghist           = (int*)alloc((size_t)Bb*128*4);             // 4 KB
    (void)ws_size; (void)in_sizes; (void)n_in; (void)out_size;

    hipMemsetAsync(ghist, 0, (size_t)Bb*128*4, stream);
    k1_scores<<<Bb*128, 256, 0, stream>>>(data, sc16, ghist);
    kB<<<Bb, 1024, 0, stream>>>(sc16, ghist, data, anchors, etab, out);
}

// Round 14
// 149.561 us; speedup vs baseline: 1.5575x; 1.5575x over previous
//
#include <hip/hip_runtime.h>
#include <stdint.h>

#define Bb 8
#define PREK 1024
#define POSTK 300
#define NBIN 120            // scores 9..127 -> bin = s-9
#define NCHUNK 512          // 256-candidate chunks per batch

__device__ __forceinline__ float clampb(float v){ return fminf(fmaxf(v, 0.0f), 1024.0f); }

// K1: best score + first-argmax per anchor (int4 vectorized), packed u16 [(s+128)<<8|lab]
//     layout sc16[b][a][h*128+w]; per-32w-chunk histogram -> chist[(b*512+ci)*120+bin]
__global__ void __launch_bounds__(256) k1_scores(const int* __restrict__ data,
                                                 unsigned short* __restrict__ sc16,
                                                 int* __restrict__ chist){
    int blk = blockIdx.x;                 // 8*128: (b, h)
    int b = blk >> 7, h = blk & 127;
    int tid = threadIdx.x;
    int a = tid >> 5, wg = tid & 31;
    int w = wg << 2;
    const int* p = data + (((size_t)(b*96 + a*12 + 4)) << 14) + (h << 7) + w;
    int4 m = *(const int4*)p;
    int4 lb = make_int4(0,0,0,0);
#pragma unroll
    for (int c = 1; c < 8; ++c){
        int4 v = *(const int4*)(p + ((size_t)c << 14));
        if (v.x > m.x){ m.x = v.x; lb.x = c; }
        if (v.y > m.y){ m.y = v.y; lb.y = c; }
        if (v.z > m.z){ m.z = v.z; lb.z = c; }
        if (v.w > m.w){ m.w = v.w; lb.w = c; }
    }
    ushort4 st;
    st.x = (unsigned short)(((m.x + 128) << 8) | lb.x);
    st.y = (unsigned short)(((m.y + 128) << 8) | lb.y);
    st.z = (unsigned short)(((m.z + 128) << 8) | lb.z);
    st.w = (unsigned short)(((m.w + 128) << 8) | lb.w);
    *(ushort4*)(sc16 + (((size_t)(b*8 + a)) << 14) + (h << 7) + w) = st;

    __shared__ int hist[4][NBIN];
    for (int i = tid; i < 4*NBIN; i += 256) ((int*)hist)[i] = 0;
    __syncthreads();
    int q = wg >> 3;
    if (m.x >= 9) atomicAdd(&hist[q][m.x-9], 1);
    if (m.y >= 9) atomicAdd(&hist[q][m.y-9], 1);
    if (m.z >= 9) atomicAdd(&hist[q][m.z-9], 1);
    if (m.w >= 9) atomicAdd(&hist[q][m.w-9], 1);
    __syncthreads();
    int* cb = chist + ((size_t)(b*NCHUNK + h*4)) * NBIN;
    for (int i = tid; i < 4*NBIN; i += 256) cb[i] = ((int*)hist)[i];
}

// K2: per batch (1024 thr): coalesced 8-group histogram reduce, suffix -> gt/T,
//     init dmeta, 512-thread exclusive chunk-scan for bins >= T
__global__ void __launch_bounds__(1024) k2_select(int* __restrict__ chist, int* __restrict__ gt,
                                                  int* __restrict__ Tb_, int* __restrict__ dmeta){
    int b = blockIdx.x, tid = threadIdx.x;
    __shared__ int part[8][NBIN];
    __shared__ int hs[NBIN];
    __shared__ int suf[128];
    __shared__ int Tsh;
    __shared__ int sb[512];
    if (tid == 0) Tsh = -1;
    const int* cb = chist + (size_t)b * NCHUNK * NBIN;
    if (tid < 8*NBIN){
        int g = tid / NBIN, bin = tid - g*NBIN;
        int s = 0;
        const int* p2 = cb + (size_t)g*64*NBIN + bin;
#pragma unroll 8
        for (int ch = 0; ch < 64; ++ch) s += p2[(size_t)ch * NBIN];
        part[g][bin] = s;
    }
    __syncthreads();
    if (tid < NBIN){
        int s = 0;
#pragma unroll
        for (int g = 0; g < 8; ++g) s += part[g][tid];
        hs[tid] = s;
    }
    __syncthreads();
    int hbin = 0;
    if (tid < 128){
        hbin = (tid < NBIN) ? hs[tid] : 0;
        suf[tid] = hbin;
    }
    __syncthreads();
    for (int off = 1; off < 128; off <<= 1){
        int v = 0;
        if (tid < 128 && tid + off < 128) v = suf[tid + off];
        __syncthreads();
        if (tid < 128) suf[tid] += v;
        __syncthreads();
    }
    if (tid < NBIN){
        gt[b*128 + tid] = suf[tid] - hbin;
        if (suf[tid] >= PREK) atomicMax(&Tsh, tid);
    }
    __syncthreads();
    int T = Tsh > 0 ? Tsh : 0;
    if (tid == 0) Tb_[b] = T;
    dmeta[b*PREK + tid] = -1;
    for (int abin = T; abin < NBIN; ++abin){
        int* basep = chist + (size_t)(b*NCHUNK) * NBIN + abin;
        int v = 0;
        if (tid < 512){ v = basep[(size_t)tid * NBIN]; sb[tid] = v; }
        __syncthreads();
        for (int off = 1; off < 512; off <<= 1){
            int a2 = 0;
            if (tid < 512 && tid >= off) a2 = sb[tid - off];
            __syncthreads();
            if (tid < 512) sb[tid] += a2;
            __syncthreads();
        }
        if (tid < 512) basep[(size_t)tid * NBIN] = sb[tid] - v;
        __syncthreads();
    }
}

// K3: stable rank via ballots + cross-wave hist; ranked candidates decode their box
//     bit-exact and scatter dbox/dmeta by rank
__global__ void __launch_bounds__(256) k3_rank(const unsigned short* __restrict__ sc16,
                                               const int* __restrict__ chist,
                                               const int* __restrict__ gt, const int* __restrict__ Tb_,
                                               const int* __restrict__ data,
                                               const float* __restrict__ anchors,
                                               const int* __restrict__ etab,
                                               float4* __restrict__ dbox, int* __restrict__ dmeta){
    int blk = blockIdx.x;                // 8*512: (b, ci)
    int b = blk >> 9, ci = blk & 511;
    int tid = threadIdx.x;
    int h = ci >> 2, w0 = (ci & 3) << 5;
    __shared__ unsigned short sc[256];
    __shared__ int wcnt[4][NBIN];
    if (tid < 64){
        int a = tid & 7, wq = tid >> 3;
        ushort4 v4 = *(const ushort4*)(sc16 + (((size_t)(b*8 + a)) << 14) + (h << 7) + w0 + (wq << 2));
        sc[(wq*4 + 0)*8 + a] = v4.x;
        sc[(wq*4 + 1)*8 + a] = v4.y;
        sc[(wq*4 + 2)*8 + a] = v4.z;
        sc[(wq*4 + 3)*8 + a] = v4.w;
    }
    for (int i = tid; i < 4*NBIN; i += 256) ((int*)wcnt)[i] = 0;
    int T = Tb_[b];
    __syncthreads();
    unsigned short v = sc[tid];
    int s = (int)(v >> 8) - 128;
    int bin = s - 9;
    bool qual = (bin >= T);
    int wv = tid >> 6, lane = tid & 63;
    if (qual) atomicAdd(&wcnt[wv][bin], 1);
    __syncthreads();
    int myeq = 0;
    {
        unsigned long long low = (1ull << lane) - 1ull;
        for (int vb = T; vb < NBIN; ++vb){
            unsigned long long bal = __ballot(qual && bin == vb);
            if (!bal) continue;
            if (qual && bin == vb) myeq = __popcll(bal & low);
        }
    }
    if (!qual) return;
    int cross = 0;
    for (int w2 = 0; w2 < wv; ++w2) cross += wcnt[w2][bin];
    int rank = gt[b*128 + bin] + chist[((size_t)(b*NCHUNK) + ci)*NBIN + bin] + cross + myeq;
    if (rank < PREK){
        int n = ci*256 + tid;               // == ((h*128+w)*8 + a)
        int a = n & 7, wc = (n >> 3) & 127;
        const int* p = data + (((size_t)(b*96 + a*12)) << 14) + (h << 7) + wc;
        int d0 = p[0], d1 = p[1 << 14], d2 = p[2 << 14], d3 = p[3 << 14];
        float4 an = ((const float4*)anchors)[n];
        float cx = __fmul_rn(__fadd_rn(an.x, an.z), 0.5f);
        float cy = __fmul_rn(__fadd_rn(an.y, an.w), 0.5f);
        float wx = __fsub_rn(an.z, an.x), wy = __fsub_rn(an.w, an.y);
        float dx = __fmul_rn((float)d0, 0.0625f), dy = __fmul_rn((float)d1, 0.0625f);
        float ex = __fmul_rn((float)etab[d2 + 128], 0.0625f);
        float ey = __fmul_rn((float)etab[d3 + 128], 0.0625f);
        float pcx = __fadd_rn(cx, __fmul_rn(dx, wx));
        float pcy = __fadd_rn(cy, __fmul_rn(dy, wy));
        float hx = __fmul_rn(__fmul_rn(wx, ex), 0.5f);
        float hy = __fmul_rn(__fmul_rn(wy, ey), 0.5f);
        float x1 = clampb(__fsub_rn(pcx, hx)), y1 = clampb(__fsub_rn(pcy, hy));
        float x2 = clampb(__fadd_rn(pcx, hx)), y2 = clampb(__fadd_rn(pcy, hy));
        dbox[b*PREK + rank] = make_float4(x1, y1, x2, y2);
        dmeta[b*PREK + rank] = (int)v;
    }
}

// K45: per batch (1024 thr): stable per-class partition, COOPERATIVE bit-matrix build
//      (each thread owns one row; ALL 4 words written — zeros included), per-class-wave
//      register walk with row prefetch, ballot compaction to 300.
__global__ void __launch_bounds__(1024) k45_nms_out(const float4* __restrict__ dbox,
                                                    const int* __restrict__ dmeta,
                                                    float* __restrict__ out){
    int b = blockIdx.x, tid = threadIdx.x, lane = tid & 63, wv = tid >> 6;
    __shared__ float X1[1024], Y1[1024], X2[1024], Y2[1024], AR[1024];
    __shared__ unsigned long long MAT[1024][4];   // 32 KB suppression bit-matrix
    __shared__ signed char CLS[1024];
    __shared__ unsigned char KEEP[1024];
    __shared__ int wq[16][8];
    __shared__ int cbs[8], ccn[8];
    __shared__ int wcn[16];
    __shared__ int totS;

    // ---- phase 1: read rank-ordered decoded boxes, stable per-class partition ----
    int v = dmeta[b*PREK + tid];
    float4 bb = dbox[b*PREK + tid];
    bool valid = (v >= 0);
    int lc = valid ? (v & 255) : -1;
    float sval = valid ? __fmul_rn((float)((v >> 8) - 128), 0.0625f) : 0.0f;
    KEEP[tid] = 0;
    CLS[tid] = -1;
    int win = 0;
#pragma unroll
    for (int c = 0; c < 8; ++c){
        unsigned long long bal = __ballot(lc == c);
        if (lane == 0) wq[wv][c] = __popcll(bal);
        if (lc == c) win = __popcll(bal & ((1ull << lane) - 1ull));
    }
    __syncthreads();
    if (tid < 8){
        int run = 0;
        for (int w2 = 0; w2 < 16; ++w2){ int t = wq[w2][tid]; wq[w2][tid] = run; run += t; }
        ccn[tid] = run;
    }
    __syncthreads();
    if (tid == 0){
        int run = 0;
        for (int c = 0; c < 8; ++c){ cbs[c] = run; run += ccn[c]; }
    }
    __syncthreads();
    int p = 0;
    if (valid){
        p = cbs[lc] + wq[wv][lc] + win;
        float off = (float)(lc << 12);
        float ox1 = __fadd_rn(bb.x, off), oy1 = __fadd_rn(bb.y, off);
        float ox2 = __fadd_rn(bb.z, off), oy2 = __fadd_rn(bb.w, off);
        X1[p] = ox1; Y1[p] = oy1; X2[p] = ox2; Y2[p] = oy2;
        AR[p] = __fmul_rn(__fsub_rn(ox2, ox1), __fsub_rn(oy2, oy1));
        CLS[p] = (signed char)lc;
    }
    __syncthreads();

    // ---- phase 2a: cooperative build — thread tid owns row slot tid; write ALL words ----
    {
        int c = CLS[tid];
        if (c >= 0){
            int base = cbs[c], M = ccn[c];
            if (M <= 256){
                int i = tid - base;
                float xi1 = X1[tid], yi1 = Y1[tid], xi2 = X2[tid], yi2 = Y2[tid], ai = AR[tid];
                int w0 = i >> 6;
                int NW = (M + 63) >> 6;
#pragma unroll
                for (int w = 0; w < 4; ++w){
                    unsigned long long bits = 0ull;
                    if (w >= w0 && w < NW){
                        int jb = w << 6;
                        int lim = M - jb; if (lim > 64) lim = 64;
                        for (int jl = 0; jl < lim; ++jl){
                            int j = jb + jl;
                            if (j > i){
                                int aj = base + j;
                                float wx = fmaxf(__fsub_rn(fminf(xi2, X2[aj]), fmaxf(xi1, X1[aj])), 0.0f);
                                float wy = fmaxf(__fsub_rn(fminf(yi2, Y2[aj]), fmaxf(yi1, Y1[aj])), 0.0f);
                                float inter = __fmul_rn(wx, wy);
                                float den = __fadd_rn(__fsub_rn(__fadd_rn(ai, AR[aj]), inter), 1e-9f);
                                if (__fdiv_rn(inter, den) > 0.5f) bits |= (1ull << jl);
                            }
                        }
                    }
                    MAT[tid][w] = bits;        // zero words written too — walk reads all 4
                }
            }
        }
    }
    __syncthreads();

    // ---- phase 2b: walk, one wave per class; replicated regs; LDS broadcast + prefetch ----
    if (wv < 8){
        int M = ccn[wv], base = cbs[wv];
        if (M > 0 && M <= 256){
            int NW = (M + 63) >> 6;
            unsigned long long rem0=0ull, rem1=0ull, rem2=0ull, rem3=0ull;
            unsigned long long nx0 = MAT[base][0], nx1 = MAT[base][1];
            unsigned long long nx2 = MAT[base][2], nx3 = MAT[base][3];
            for (int iw = 0; iw < NW; ++iw){
                int limi = M - (iw << 6); if (limi > 64) limi = 64;
                for (int il = 0; il < limi; ++il){
                    unsigned long long c0=nx0, c1=nx1, c2=nx2, c3=nx3;
                    int r = base + (iw << 6) + il;
                    int rn = (r + 1 < base + M) ? r + 1 : r;
                    nx0 = MAT[rn][0]; nx1 = MAT[rn][1]; nx2 = MAT[rn][2]; nx3 = MAT[rn][3];
                    unsigned long long cur = (iw==0)?rem0:(iw==1)?rem1:(iw==2)?rem2:rem3;
                    if (!((cur >> il) & 1ull)){
                        rem0 |= c0; rem1 |= c1; rem2 |= c2; rem3 |= c3;
                    }
                }
            }
            {
                int r = lane;
                if (r       < M) KEEP[base+r]     = (unsigned char)(((rem0 >> lane) & 1ull) ^ 1ull);
                if (r + 64  < M) KEEP[base+r+64]  = (unsigned char)(((rem1 >> lane) & 1ull) ^ 1ull);
                if (r + 128 < M) KEEP[base+r+128] = (unsigned char)(((rem2 >> lane) & 1ull) ^ 1ull);
                if (r + 192 < M) KEEP[base+r+192] = (unsigned char)(((rem3 >> lane) & 1ull) ^ 1ull);
            }
        } else if (M > 256){
            // fallback: wave-serial greedy in LDS
            for (int m = lane; m < M; m += 64) KEEP[base+m] = 0;   // 1 = suppressed
            for (int i = 0; i < M; ++i){
                if (KEEP[base+i]) continue;
                float xi1 = X1[base+i], yi1 = Y1[base+i];
                float xi2 = X2[base+i], yi2 = Y2[base+i], ai = AR[base+i];
                for (int j = i + 1 + lane; j < M; j += 64){
                    if (KEEP[base+j]) continue;
                    float wx = fmaxf(__fsub_rn(fminf(xi2, X2[base+j]), fmaxf(xi1, X1[base+j])), 0.0f);
                    float wy = fmaxf(__fsub_rn(fminf(yi2, Y2[base+j]), fmaxf(yi1, Y1[base+j])), 0.0f);
                    float inter = __fmul_rn(wx, wy);
                    float den = __fadd_rn(__fsub_rn(__fadd_rn(ai, AR[base+j]), inter), 1e-9f);
                    if (__fdiv_rn(inter, den) > 0.5f) KEEP[base+j] = 1;
                }
            }
            for (int m = lane; m < M; m += 64) KEEP[base+m] ^= 1;  // -> 1 = keep
        }
    }
    __syncthreads();

    // ---- phase 3: rank-ordered compaction to first 300 ----
    bool kp = valid && (KEEP[p] != 0);
    unsigned long long bal = __ballot(kp);
    if (lane == 0) wcn[wv] = __popcll(bal);
    __syncthreads();
    if (tid == 0){
        int r = 0;
        for (int w2 = 0; w2 < 16; ++w2){ int t = wcn[w2]; wcn[w2] = r; r += t; }
        totS = r;
    }
    __syncthreads();
    int pos = wcn[wv] + __popcll(bal & ((1ull << lane) - 1ull));
    float* boxes  = out;
    float* scores = out + Bb*POSTK*4;
    float* labs   = out + Bb*POSTK*5;
    if (kp && pos < POSTK){
        int o = (b*POSTK + pos)*4;
        boxes[o+0] = bb.x; boxes[o+1] = bb.y; boxes[o+2] = bb.z; boxes[o+3] = bb.w;
        scores[b*POSTK + pos] = sval;
        labs[b*POSTK + pos] = (float)lc;
    }
    int tot = totS < POSTK ? totS : POSTK;
    if (tid >= tot && tid < POSTK){
        int o = (b*POSTK + tid)*4;
        boxes[o+0] = 0.f; boxes[o+1] = 0.f; boxes[o+2] = 0.f; boxes[o+3] = 0.f;
        scores[b*POSTK + tid] = 0.f;
        labs[b*POSTK + tid] = -1.0f;
    }
}

extern "C" void kernel_launch(void* const* d_in, const int* in_sizes, int n_in,
                              void* d_out, int out_size, void* d_ws, size_t ws_size,
                              hipStream_t stream) {
    const int*   data    = (const int*)d_in[0];
    const float* anchors = (const float*)d_in[1];
    const int*   etab    = (const int*)d_in[2];
    float* out = (float*)d_out;

    char* ws = (char*)d_ws;
    size_t off = 0;
    auto alloc = [&](size_t bytes)->char*{ char* p = ws + off; off += (bytes + 255) & ~(size_t)255; return p; };
    unsigned short* sc16 = (unsigned short*)alloc((size_t)Bb*8*16384*2);   // 2 MB
    int* chist           = (int*)alloc((size_t)Bb*NCHUNK*NBIN*4);          // 1.9 MB
    int* gt              = (int*)alloc((size_t)Bb*128*4);
    int* Tb_             = (int*)alloc((size_t)Bb*4);
    float4* dbox         = (float4*)alloc((size_t)Bb*PREK*16);             // 128 KB
    int* dmeta           = (int*)alloc((size_t)Bb*PREK*4);                 // 32 KB
    (void)ws_size; (void)in_sizes; (void)n_in; (void)out_size;

    k1_scores<<<Bb*128, 256, 0, stream>>>(data, sc16, chist);
    k2_select<<<Bb, 1024, 0, stream>>>(chist, gt, Tb_, dmeta);
    k3_rank<<<Bb*NCHUNK, 256, 0, stream>>>(sc16, chist, gt, Tb_, data, anchors, etab, dbox, dmeta);
    k45_nms_out<<<Bb, 1024, 0, stream>>>(dbox, dmeta, out);
}